// Round 1
// baseline (307.548 us; speedup 1.0000x reference)
//
#include <hip/hip_runtime.h>
#include <hip/hip_bf16.h>

// Problem: 1x1024x32x32 SE-block + separable-gaussian spatial pool +
// 3x3 local softmax attention + 1x1 conv + BN + ReLU.  All fp32.
// H=W=32, C=1024, r=16, V=1.5.

#define C_DIM 1024
#define HW    1024

__device__ __forceinline__ float sigmoidf_(float v) {
    return 1.f / (1.f + __expf(-v));
}

// ---------------- K1: per-channel spatial mean ----------------
__global__ __launch_bounds__(256) void k_mean(const float* __restrict__ x,
                                              float* __restrict__ mean) {
    int c = blockIdx.x;
    int tid = threadIdx.x;
    const float* xp = x + (size_t)c * HW;
    float s = xp[tid] + xp[tid + 256] + xp[tid + 512] + xp[tid + 768];
    #pragma unroll
    for (int o = 32; o; o >>= 1) s += __shfl_down(s, o);
    __shared__ float wsum[4];
    if ((tid & 63) == 0) wsum[tid >> 6] = s;
    __syncthreads();
    if (tid == 0) mean[c] = (wsum[0] + wsum[1] + wsum[2] + wsum[3]) * (1.f / 1024.f);
}

// ---------------- K2: SE MLP (64 hidden, relu -> 1024 sigmoid) ----------------
__global__ __launch_bounds__(1024) void k_mlp(const float* __restrict__ mean,
                                              const float* __restrict__ w1,
                                              const float* __restrict__ b1,
                                              const float* __restrict__ w2,
                                              const float* __restrict__ b2,
                                              float* __restrict__ y2) {
    __shared__ float y1[64];
    int tid = threadIdx.x;
    int j = tid >> 4, l = tid & 15;            // 64 outputs x 16 threads each
    float partial = 0.f;
    for (int c = l; c < 1024; c += 16)
        partial += mean[c] * w1[j * 1024 + c];
    #pragma unroll
    for (int o = 8; o; o >>= 1) partial += __shfl_down(partial, o, 16);
    if (l == 0) y1[j] = fmaxf(partial + b1[j], 0.f);
    __syncthreads();
    float acc = 0.f;
    #pragma unroll 16
    for (int jj = 0; jj < 64; ++jj) acc += y1[jj] * w2[tid * 64 + jj];
    y2[tid] = sigmoidf_(acc + b2[tid]);
}

// ---------------- K3: xr = sigmoid(x * y2[c]) ----------------
__global__ __launch_bounds__(256) void k_xr(const float* __restrict__ x,
                                            const float* __restrict__ y2,
                                            float* __restrict__ xr) {
    int idx = blockIdx.x * 256 + threadIdx.x;
    int base = idx << 2;                       // 4 floats, all in same channel
    int c = base >> 10;
    float sc = y2[c];
    float4 v = *(const float4*)(x + base);
    float4 r;
    r.x = sigmoidf_(v.x * sc);
    r.y = sigmoidf_(v.y * sc);
    r.z = sigmoidf_(v.z * sc);
    r.w = sigmoidf_(v.w * sc);
    *(float4*)(xr + base) = r;
}

// ---------------- K4: normalized 1-D gaussian matrix Ghat[32][32] ----------------
__global__ __launch_bounds__(1024) void k_ghat(float* __restrict__ G) {
    int tid = threadIdx.x;
    int i = tid >> 5, h = tid & 31;
    float d = (float)(i - h);
    float g = __expf(-d * d / 4.5f);           // 2*V*V = 4.5
    float s = g;
    #pragma unroll
    for (int o = 16; o; o >>= 1) s += __shfl_down(s, o, 32);
    s = __shfl(s, 0, 32);                      // broadcast row sum within 32-group
    G[tid] = g / s;
}

// ---------------- K5: x_spatial[c] = Ghat * (x*y2[c]) * Ghat^T ----------------
__global__ __launch_bounds__(1024) void k_spatial(const float* __restrict__ x,
                                                  const float* __restrict__ y2,
                                                  const float* __restrict__ G,
                                                  float* __restrict__ xs) {
    __shared__ float Xs[32][33];
    __shared__ float Gl[32][33];
    __shared__ float T[32][33];
    int c = blockIdx.x;
    int tid = threadIdx.x;
    int r = tid >> 5, q = tid & 31;
    float sc = y2[c];
    Xs[r][q] = x[(size_t)c * HW + tid] * sc;
    Gl[r][q] = G[tid];
    __syncthreads();
    float t = 0.f;
    #pragma unroll 8
    for (int w = 0; w < 32; ++w) t += Xs[r][w] * Gl[q][w];   // (X G^T)[r][q]
    T[r][q] = t;
    __syncthreads();
    float s = 0.f;
    #pragma unroll 8
    for (int h = 0; h < 32; ++h) s += Gl[r][h] * T[h][q];    // (G X G^T)[r][q]
    xs[(size_t)c * HW + tid] = s;
}

// ---------------- K6: per-position 3x3 local softmax attention ----------------
// val[f], f=9*c_idx+rem == 1024*q + c2 (the reference's reshape reinterpretation).
__global__ __launch_bounds__(256) void k_attn(const float* __restrict__ xr,
                                              float* __restrict__ xrange) {
    __shared__ float center[1024];
    __shared__ float val[9216];
    __shared__ float logits9[9];
    __shared__ float attn9[9];
    int p = blockIdx.x;
    int h = p >> 5, w = p & 31;
    int tid = threadIdx.x;
    if (tid < 9) logits9[tid] = 0.f;
    for (int c2 = tid; c2 < 1024; c2 += 256)
        center[c2] = xr[(size_t)c2 * HW + p];
    for (int idx = tid; idx < 9216; idx += 256) {
        int c = idx / 9;
        int rem = idx - c * 9;
        int hh = h + rem / 3 - 1;
        int ww = w + (rem % 3) - 1;
        float v = 0.f;
        if (hh >= 0 && hh < 32 && ww >= 0 && ww < 32)
            v = xr[(size_t)c * HW + (hh << 5) + ww];
        val[idx] = v;
    }
    __syncthreads();
    // logits[q] = sum_c2 center[c2]*val[q*1024+c2]
    #pragma unroll
    for (int q = 0; q < 9; ++q) {
        float f = 0.f;
        int base = q << 10;
        for (int j = tid; j < 1024; j += 256)
            f += center[j] * val[base + j];
        #pragma unroll
        for (int o = 32; o; o >>= 1) f += __shfl_down(f, o);
        if ((tid & 63) == 0) atomicAdd(&logits9[q], f);
    }
    __syncthreads();
    if (tid < 64) {
        float lg = (tid < 9) ? logits9[tid] : -3.4e38f;
        float m = lg;
        #pragma unroll
        for (int o = 32; o; o >>= 1) m = fmaxf(m, __shfl_down(m, o));
        m = __shfl(m, 0);
        float e = (tid < 9) ? __expf(lg - m) : 0.f;
        float s = e;
        #pragma unroll
        for (int o = 32; o; o >>= 1) s += __shfl_down(s, o);
        s = __shfl(s, 0);
        if (tid < 9) attn9[tid] = e / s;
    }
    __syncthreads();
    float a[9];
    #pragma unroll
    for (int q = 0; q < 9; ++q) a[q] = attn9[q];
    for (int c2 = tid; c2 < 1024; c2 += 256) {
        float r = 0.f;
        #pragma unroll
        for (int q = 0; q < 9; ++q) r += a[q] * val[(q << 10) + c2];
        xrange[(size_t)c2 * HW + p] = r;
    }
}

// ---------------- K7: out = relu(BN(W @ [x_range; x_spatial])) ----------------
// W: [1024][2048] row-major; cat columns are the 1024 spatial positions.
__global__ __launch_bounds__(256) void k_gemm(const float* __restrict__ W,
                                              const float* __restrict__ xrange,
                                              const float* __restrict__ xspatial,
                                              const float* __restrict__ gamma,
                                              const float* __restrict__ beta,
                                              const float* __restrict__ mu,
                                              const float* __restrict__ var,
                                              float* __restrict__ out) {
    __shared__ __align__(16) float Wt[16][68];   // [k][m], pad 4 -> conflict-free + 16B rows
    __shared__ __align__(16) float Ct[16][68];   // [k][n]
    int tid = threadIdx.x;
    int tx = tid & 15, ty = tid >> 4;
    int m0 = blockIdx.y << 6, n0 = blockIdx.x << 6;
    float acc[4][4] = {};
    for (int c0 = 0; c0 < 2048; c0 += 16) {
        int lk = tid & 15, lm = tid >> 4;
        #pragma unroll
        for (int mm = 0; mm < 4; ++mm)
            Wt[lk][lm + mm * 16] = W[(size_t)(m0 + lm + mm * 16) * 2048 + c0 + lk];
        const float* src = (c0 < 1024) ? (xrange + ((size_t)c0 << 10))
                                       : (xspatial + ((size_t)(c0 - 1024) << 10));
        int ln = tid & 63, lk2 = tid >> 6;
        #pragma unroll
        for (int kk = 0; kk < 4; ++kk)
            Ct[lk2 + kk * 4][ln] = src[(size_t)(lk2 + kk * 4) * 1024 + n0 + ln];
        __syncthreads();
        #pragma unroll
        for (int k = 0; k < 16; ++k) {
            float4 av4 = *(const float4*)&Wt[k][ty << 2];
            float4 bv4 = *(const float4*)&Ct[k][tx << 2];
            float av[4] = {av4.x, av4.y, av4.z, av4.w};
            float bv[4] = {bv4.x, bv4.y, bv4.z, bv4.w};
            #pragma unroll
            for (int i = 0; i < 4; ++i)
                #pragma unroll
                for (int j = 0; j < 4; ++j)
                    acc[i][j] = fmaf(av[i], bv[j], acc[i][j]);
        }
        __syncthreads();
    }
    #pragma unroll
    for (int i = 0; i < 4; ++i) {
        int o = m0 + (ty << 2) + i;
        float inv = rsqrtf(var[o] + 1e-5f);
        float sc = inv * gamma[o];
        float sh = beta[o] - mu[o] * sc;
        #pragma unroll
        for (int j = 0; j < 4; ++j) {
            int p = n0 + (tx << 2) + j;
            out[((size_t)o << 10) + p] = fmaxf(fmaf(acc[i][j], sc, sh), 0.f);
        }
    }
}

extern "C" void kernel_launch(void* const* d_in, const int* in_sizes, int n_in,
                              void* d_out, int out_size, void* d_ws, size_t ws_size,
                              hipStream_t stream) {
    const float* x     = (const float*)d_in[0];
    const float* w1    = (const float*)d_in[1];
    const float* b1    = (const float*)d_in[2];
    const float* w2    = (const float*)d_in[3];
    const float* b2    = (const float*)d_in[4];
    const float* cw    = (const float*)d_in[5];
    const float* gamma = (const float*)d_in[6];
    const float* beta  = (const float*)d_in[7];
    const float* mu    = (const float*)d_in[8];
    const float* var   = (const float*)d_in[9];
    float* wsf  = (float*)d_ws;
    float* xr   = wsf;                       // [1024*1024]
    float* xs   = wsf + (1 << 20);           // [1024*1024]
    float* xrg  = wsf + (2 << 20);           // [1024*1024]
    float* mean = wsf + (3 << 20);           // [1024]
    float* y2   = mean + 1024;               // [1024]
    float* G    = y2 + 1024;                 // [1024]
    float* out  = (float*)d_out;

    k_mean   <<<1024, 256, 0, stream>>>(x, mean);
    k_mlp    <<<1, 1024, 0, stream>>>(mean, w1, b1, w2, b2, y2);
    k_xr     <<<1024, 256, 0, stream>>>(x, y2, xr);
    k_ghat   <<<1, 1024, 0, stream>>>(G);
    k_spatial<<<1024, 1024, 0, stream>>>(x, y2, G, xs);
    k_attn   <<<1024, 256, 0, stream>>>(xr, xrg);
    dim3 gg(16, 16);
    k_gemm   <<<gg, 256, 0, stream>>>(cw, xrg, xs, gamma, beta, mu, var, out);
}

// Round 2
// 157.750 us; speedup vs baseline: 1.9496x; 1.9496x over previous
//
#include <hip/hip_runtime.h>
#include <hip/hip_bf16.h>

// 1x1024x32x32: SE block + separable-gaussian spatial pool (as bf16 MFMA GEMM)
// + 3x3 local softmax attention + 1x1 conv/BN/ReLU (bf16 MFMA GEMM).
// H=W=32, C=1024, r=16, V=1.5.

#define HW 1024

typedef __attribute__((ext_vector_type(8))) short v8s;
typedef __attribute__((ext_vector_type(4))) float v4f;

__device__ __forceinline__ float sigmoidf_(float v) {
    return 1.f / (1.f + __expf(-v));
}
__device__ __forceinline__ unsigned short f2bf(float f) {
    unsigned u = __float_as_uint(f);
    u += 0x7fffu + ((u >> 16) & 1u);
    return (unsigned short)(u >> 16);
}

// ---------------- K1: per-channel spatial mean ----------------
__global__ __launch_bounds__(256) void k_mean(const float* __restrict__ x,
                                              float* __restrict__ mean) {
    int c = blockIdx.x;
    int tid = threadIdx.x;
    const float* xp = x + (size_t)c * HW;
    float s = xp[tid] + xp[tid + 256] + xp[tid + 512] + xp[tid + 768];
    #pragma unroll
    for (int o = 32; o; o >>= 1) s += __shfl_down(s, o);
    __shared__ float wsum[4];
    if ((tid & 63) == 0) wsum[tid >> 6] = s;
    __syncthreads();
    if (tid == 0) mean[c] = (wsum[0] + wsum[1] + wsum[2] + wsum[3]) * (1.f / 1024.f);
}

// ---------------- K2: SE MLP ----------------
__global__ __launch_bounds__(1024) void k_mlp(const float* __restrict__ mean,
                                              const float* __restrict__ w1,
                                              const float* __restrict__ b1,
                                              const float* __restrict__ w2,
                                              const float* __restrict__ b2,
                                              float* __restrict__ y2) {
    __shared__ float y1[64];
    int tid = threadIdx.x;
    int j = tid >> 4, l = tid & 15;
    float partial = 0.f;
    for (int c = l; c < 1024; c += 16)
        partial += mean[c] * w1[j * 1024 + c];
    #pragma unroll
    for (int o = 8; o; o >>= 1) partial += __shfl_down(partial, o, 16);
    if (l == 0) y1[j] = fmaxf(partial + b1[j], 0.f);
    __syncthreads();
    float acc = 0.f;
    #pragma unroll 16
    for (int jj = 0; jj < 64; ++jj) acc += y1[jj] * w2[tid * 64 + jj];
    y2[tid] = sigmoidf_(acc + b2[tid]);
}

// ---------------- K3: normalized 1-D gaussian Ghat[32][32] ----------------
__global__ __launch_bounds__(1024) void k_ghat(float* __restrict__ G) {
    int tid = threadIdx.x;
    int i = tid >> 5, h = tid & 31;
    float d = (float)(i - h);
    float g = __expf(-d * d / 4.5f);
    float s = g;
    #pragma unroll
    for (int o = 16; o; o >>= 1) s += __shfl_down(s, o, 32);
    s = __shfl(s, 0, 32);
    G[tid] = g / s;
}

// ---------------- K4: K2[p][hw] = Ghat[r][h]*Ghat[q][w]  (bf16) ----------------
__global__ __launch_bounds__(256) void k_k2(const float* __restrict__ G,
                                            unsigned short* __restrict__ K2) {
    int p = blockIdx.x;
    int r = p >> 5, q = p & 31;
    __shared__ float Gr[32], Gq[32];
    int tid = threadIdx.x;
    if (tid < 32) Gr[tid] = G[r * 32 + tid];
    else if (tid < 64) Gq[tid - 32] = G[q * 32 + (tid - 32)];
    __syncthreads();
    #pragma unroll
    for (int j = 0; j < 4; ++j) {
        int hw = tid + 256 * j;
        int hh = hw >> 5, ww = hw & 31;
        K2[(size_t)p * 1024 + hw] = f2bf(Gr[hh] * Gq[ww]);
    }
}

// ---------------- K5: Xsb[c][hw] = bf16(x * y2[c]) ----------------
__global__ __launch_bounds__(256) void k_xsb(const float* __restrict__ x,
                                             const float* __restrict__ y2,
                                             unsigned short* __restrict__ Xsb) {
    int e = (blockIdx.x * 256 + threadIdx.x) << 2;
    int c = e >> 10;
    float sc = y2[c];
    float4 v = *(const float4*)(x + e);
    uint2 w2;
    w2.x = (unsigned)f2bf(v.x * sc) | ((unsigned)f2bf(v.y * sc) << 16);
    w2.y = (unsigned)f2bf(v.z * sc) | ((unsigned)f2bf(v.w * sc) << 16);
    *(uint2*)(Xsb + e) = w2;
}

// ---------------- K6: xr_t[p][c] = sigmoid(x[c][p]*y2[c])  (fp32, transposed) ----------------
__global__ __launch_bounds__(256) void k_xrT(const float* __restrict__ x,
                                             const float* __restrict__ y2,
                                             float* __restrict__ xr_t) {
    __shared__ float T[32][33];
    int tx = threadIdx.x & 31, ty = threadIdx.x >> 5;  // ty 0..7
    int c0 = blockIdx.x << 5, p0 = blockIdx.y << 5;
    #pragma unroll
    for (int i = 0; i < 4; ++i) {
        int cc = ty + i * 8;
        float v = x[(size_t)(c0 + cc) * 1024 + p0 + tx];
        T[cc][tx] = sigmoidf_(v * y2[c0 + cc]);
    }
    __syncthreads();
    #pragma unroll
    for (int i = 0; i < 4; ++i) {
        int pp = ty + i * 8;
        xr_t[(size_t)(p0 + pp) * 1024 + c0 + tx] = T[tx][pp];
    }
}

// ---------------- K7: 3x3 local softmax attention -> Bt[p][0:1024] bf16 ----------------
// Preserves the reference's reshape reinterpretation: flat feature f = 9*cf + rem
// is consumed as f = 1024*q + c2.
__global__ __launch_bounds__(256) void k_attn(const float* __restrict__ xr_t,
                                              unsigned short* __restrict__ Bt) {
    __shared__ float val[9216];
    __shared__ float part[9][4];
    int p = blockIdx.x;
    int h = p >> 5, w = p & 31;
    int tid = threadIdx.x;
    int wv = tid >> 6, lane = tid & 63;
    // fill val[9*cf + rem] = xr_t[neighbor(rem)][cf]
    #pragma unroll
    for (int rem = 0; rem < 9; ++rem) {
        int dh = rem / 3 - 1, dw = rem % 3 - 1;
        bool ok = ((unsigned)(h + dh) < 32u) && ((unsigned)(w + dw) < 32u);
        const float* row = xr_t + (size_t)((h + dh) * 32 + (w + dw)) * 1024;
        #pragma unroll
        for (int j = 0; j < 4; ++j) {
            int cf = tid + 256 * j;
            val[cf * 9 + rem] = ok ? row[cf] : 0.f;
        }
    }
    __syncthreads();
    float4 ctr = *(const float4*)(xr_t + (size_t)p * 1024 + 4 * tid);
    float4 vq[9];
    float lg[9];
    #pragma unroll
    for (int q = 0; q < 9; ++q) {
        float4 v = *(const float4*)&val[q * 1024 + 4 * tid];
        vq[q] = v;
        lg[q] = ctr.x * v.x + ctr.y * v.y + ctr.z * v.z + ctr.w * v.w;
    }
    #pragma unroll
    for (int q = 0; q < 9; ++q) {
        float s = lg[q];
        #pragma unroll
        for (int o = 32; o; o >>= 1) s += __shfl_down(s, o);
        if (lane == 0) part[q][wv] = s;
    }
    __syncthreads();
    float a9[9], mx = -3.4e38f;
    #pragma unroll
    for (int q = 0; q < 9; ++q) {
        a9[q] = part[q][0] + part[q][1] + part[q][2] + part[q][3];
        mx = fmaxf(mx, a9[q]);
    }
    float se = 0.f;
    #pragma unroll
    for (int q = 0; q < 9; ++q) { a9[q] = __expf(a9[q] - mx); se += a9[q]; }
    float inv = 1.f / se;
    float4 o4 = {0.f, 0.f, 0.f, 0.f};
    #pragma unroll
    for (int q = 0; q < 9; ++q) {
        float a = a9[q] * inv;
        o4.x += a * vq[q].x; o4.y += a * vq[q].y;
        o4.z += a * vq[q].z; o4.w += a * vq[q].w;
    }
    uint2 w2;
    w2.x = (unsigned)f2bf(o4.x) | ((unsigned)f2bf(o4.y) << 16);
    w2.y = (unsigned)f2bf(o4.z) | ((unsigned)f2bf(o4.w) << 16);
    *(uint2*)(Bt + (size_t)p * 2048 + 4 * tid) = w2;
}

// ---------------- K8: W fp32 -> bf16 ----------------
__global__ __launch_bounds__(256) void k_packW(const float* __restrict__ W,
                                               unsigned short* __restrict__ Wb) {
    int e = (blockIdx.x * 256 + threadIdx.x) << 2;
    float4 v = *(const float4*)(W + e);
    uint2 w2;
    w2.x = (unsigned)f2bf(v.x) | ((unsigned)f2bf(v.y) << 16);
    w2.y = (unsigned)f2bf(v.z) | ((unsigned)f2bf(v.w) << 16);
    *(uint2*)(Wb + e) = w2;
}

// ---------------- K9: MFMA GEMM, C[m][n] = sum_k A[m][k]*B[n][k] ----------------
// 64x64 tile, BK=64, 4 waves (2x2), 2x2 frags of 16x16x32 per wave.
// MODE 0: main conv GEMM -> out fp32 with BN+ReLU (out[m*1024+n])
// MODE 1: spatial GEMM   -> Bt[m*2048 + 1024 + n] bf16
template <int MODE>
__global__ __launch_bounds__(256) void k_gemm_mfma(
    const unsigned short* __restrict__ A, const unsigned short* __restrict__ B,
    int K, float* __restrict__ outF, unsigned short* __restrict__ outB,
    const float* __restrict__ gamma, const float* __restrict__ beta,
    const float* __restrict__ mu, const float* __restrict__ var) {
    __shared__ unsigned short As[64 * 72];   // 144B rows: 16B-aligned, bank-spread
    __shared__ unsigned short Bs[64 * 72];
    int tid = threadIdx.x;
    int wv = tid >> 6, lane = tid & 63;
    int wm = wv & 1, wn = wv >> 1;
    int m0 = blockIdx.y << 6, n0 = blockIdx.x << 6;
    int col = lane & 15, quad = lane >> 4;
    // staging: thread loads 2 consecutive 8-elem granules of one row (A and B)
    int sm = tid >> 2;            // 0..63
    int sg = (tid & 3) * 2;       // 0,2,4,6
    v4f acc[2][2];
    #pragma unroll
    for (int i = 0; i < 2; ++i)
        #pragma unroll
        for (int j = 0; j < 2; ++j) acc[i][j] = (v4f){0.f, 0.f, 0.f, 0.f};

    float4 ra0, ra1, rb0, rb1;
    const float4* pa;
    const float4* pb;
    pa = (const float4*)(A + (size_t)(m0 + sm) * K + sg * 8);
    pb = (const float4*)(B + (size_t)(n0 + sm) * K + sg * 8);
    ra0 = pa[0]; ra1 = pa[1];
    rb0 = pb[0]; rb1 = pb[1];
    int nIter = K >> 6;
    for (int it = 0; it < nIter; ++it) {
        __syncthreads();
        *(float4*)&As[sm * 72 + sg * 8] = ra0;
        *(float4*)&As[sm * 72 + sg * 8 + 8] = ra1;
        *(float4*)&Bs[sm * 72 + sg * 8] = rb0;
        *(float4*)&Bs[sm * 72 + sg * 8 + 8] = rb1;
        __syncthreads();
        if (it + 1 < nIter) {
            int k0 = (it + 1) << 6;
            pa = (const float4*)(A + (size_t)(m0 + sm) * K + k0 + sg * 8);
            pb = (const float4*)(B + (size_t)(n0 + sm) * K + k0 + sg * 8);
            ra0 = pa[0]; ra1 = pa[1];
            rb0 = pb[0]; rb1 = pb[1];
        }
        #pragma unroll
        for (int ks = 0; ks < 2; ++ks) {
            int kg = ks * 4 + quad;
            int rA = wm * 32 + col;
            int rB = wn * 32 + col;
            v8s a0 = *(const v8s*)&As[rA * 72 + kg * 8];
            v8s a1 = *(const v8s*)&As[(rA + 16) * 72 + kg * 8];
            v8s b0 = *(const v8s*)&Bs[rB * 72 + kg * 8];
            v8s b1 = *(const v8s*)&Bs[(rB + 16) * 72 + kg * 8];
            acc[0][0] = __builtin_amdgcn_mfma_f32_16x16x32_bf16(a0, b0, acc[0][0], 0, 0, 0);
            acc[0][1] = __builtin_amdgcn_mfma_f32_16x16x32_bf16(a0, b1, acc[0][1], 0, 0, 0);
            acc[1][0] = __builtin_amdgcn_mfma_f32_16x16x32_bf16(a1, b0, acc[1][0], 0, 0, 0);
            acc[1][1] = __builtin_amdgcn_mfma_f32_16x16x32_bf16(a1, b1, acc[1][1], 0, 0, 0);
        }
    }
    // epilogue: D row m = quad*4+reg (+frag offs), col n = lane&15 (+frag offs)
    #pragma unroll
    for (int mi = 0; mi < 2; ++mi) {
        #pragma unroll
        for (int ni = 0; ni < 2; ++ni) {
            int mb = m0 + wm * 32 + mi * 16 + quad * 4;
            int nn = n0 + wn * 32 + ni * 16 + col;
            #pragma unroll
            for (int r = 0; r < 4; ++r) {
                int mm = mb + r;
                if (MODE == 0) {
                    float iv = rsqrtf(var[mm] + 1e-5f);
                    float sc = iv * gamma[mm];
                    float sh = beta[mm] - mu[mm] * sc;
                    outF[((size_t)mm << 10) + nn] =
                        fmaxf(fmaf(acc[mi][ni][r], sc, sh), 0.f);
                } else {
                    outB[(size_t)mm * 2048 + 1024 + nn] = f2bf(acc[mi][ni][r]);
                }
            }
        }
    }
}

extern "C" void kernel_launch(void* const* d_in, const int* in_sizes, int n_in,
                              void* d_out, int out_size, void* d_ws, size_t ws_size,
                              hipStream_t stream) {
    const float* x     = (const float*)d_in[0];
    const float* w1    = (const float*)d_in[1];
    const float* b1    = (const float*)d_in[2];
    const float* w2    = (const float*)d_in[3];
    const float* b2    = (const float*)d_in[4];
    const float* cw    = (const float*)d_in[5];
    const float* gamma = (const float*)d_in[6];
    const float* beta  = (const float*)d_in[7];
    const float* mu    = (const float*)d_in[8];
    const float* var   = (const float*)d_in[9];
    float* wsf = (float*)d_ws;
    // layout (floats): [0,1M): xr_t fp32, later overlaid by Wb bf16 (2M ushort)
    //                  [1M,2M): Bt bf16 [1024][2048]
    //                  [2M,2.5M): K2 bf16 [1024][1024]
    //                  [2.5M,3M): Xsb bf16 [1024][1024]
    //                  [3M,..): mean, y2, G
    float*          xr_t = wsf;
    unsigned short* Wb   = (unsigned short*)wsf;
    unsigned short* Bt   = (unsigned short*)(wsf + (1 << 20));
    unsigned short* K2   = (unsigned short*)(wsf + (2 << 20));
    unsigned short* Xsb  = (unsigned short*)(wsf + (2 << 20) + (1 << 19));
    float* mean = wsf + (3 << 20);
    float* y2   = mean + 1024;
    float* G    = y2 + 1024;
    float* out  = (float*)d_out;

    k_mean <<<1024, 256, 0, stream>>>(x, mean);
    k_mlp  <<<1, 1024, 0, stream>>>(mean, w1, b1, w2, b2, y2);
    k_ghat <<<1, 1024, 0, stream>>>(G);
    k_k2   <<<1024, 256, 0, stream>>>(G, K2);
    k_xsb  <<<1024, 256, 0, stream>>>(x, y2, Xsb);
    dim3 gg(16, 16);
    // spatial pool: Bt[p][1024+c] = sum_hw K2[p][hw] * Xsb[c][hw]
    k_gemm_mfma<1><<<gg, 256, 0, stream>>>(K2, Xsb, 1024, nullptr, Bt,
                                           nullptr, nullptr, nullptr, nullptr);
    dim3 gt(32, 32);
    k_xrT  <<<gt, 256, 0, stream>>>(x, y2, xr_t);
    k_attn <<<1024, 256, 0, stream>>>(xr_t, Bt);
    k_packW<<<2048, 256, 0, stream>>>(cw, Wb);   // overlays xr_t (dead after k_attn)
    // main: out = relu(BN(Wb[o][k] . Bt[p][k]))
    k_gemm_mfma<0><<<gg, 256, 0, stream>>>(Wb, Bt, 2048, out, nullptr,
                                           gamma, beta, mu, var);
}

// Round 3
// 136.882 us; speedup vs baseline: 2.2468x; 1.1525x over previous
//
#include <hip/hip_runtime.h>
#include <hip/hip_bf16.h>

// 1x1024x32x32: SE block + separable-gaussian spatial pool (A generated in-GEMM)
// + 3x3 local softmax attention (bf16) + 1x1 conv/BN/ReLU (bf16 MFMA GEMM).
// H=W=32, C=1024, r=16, V=1.5.

typedef __attribute__((ext_vector_type(8))) short v8s;
typedef __attribute__((ext_vector_type(4))) float v4f;

__device__ __forceinline__ float sigmoidf_(float v) {
    return 1.f / (1.f + __expf(-v));
}
__device__ __forceinline__ unsigned short f2bf(float f) {
    unsigned u = __float_as_uint(f);
    u += 0x7fffu + ((u >> 16) & 1u);
    return (unsigned short)(u >> 16);
}
__device__ __forceinline__ float bf2f(unsigned short s) {
    return __uint_as_float(((unsigned)s) << 16);
}

// ---------------- K1: per-channel spatial mean ----------------
__global__ __launch_bounds__(256) void k_mean(const float* __restrict__ x,
                                              float* __restrict__ mean) {
    int c = blockIdx.x;
    int tid = threadIdx.x;
    const float* xp = x + (size_t)c * 1024;
    float s = xp[tid] + xp[tid + 256] + xp[tid + 512] + xp[tid + 768];
    #pragma unroll
    for (int o = 32; o; o >>= 1) s += __shfl_down(s, o);
    __shared__ float wsum[4];
    if ((tid & 63) == 0) wsum[tid >> 6] = s;
    __syncthreads();
    if (tid == 0) mean[c] = (wsum[0] + wsum[1] + wsum[2] + wsum[3]) * (1.f / 1024.f);
}

// ---------------- K2: SE MLP, parallel (16 blocks x 64 outputs) ----------------
// Layer 1 (64 hidden) computed redundantly per block with full-wave coalesced dots;
// layer 2 from an LDS-staged w2 tile.
__global__ __launch_bounds__(256) void k_se(const float* __restrict__ mean,
                                            const float* __restrict__ w1,
                                            const float* __restrict__ b1,
                                            const float* __restrict__ w2,
                                            const float* __restrict__ b2,
                                            float* __restrict__ y2) {
    __shared__ float ms[1024];
    __shared__ float y1[64];
    __shared__ float w2t[64 * 65];
    int tid = threadIdx.x;
    int c0 = blockIdx.x << 6;
    #pragma unroll
    for (int i = 0; i < 4; ++i) ms[tid + (i << 8)] = mean[tid + (i << 8)];
    #pragma unroll
    for (int i = 0; i < 16; ++i) {
        int idx = tid + (i << 8);                       // 4096 floats
        w2t[(idx >> 6) * 65 + (idx & 63)] = w2[(size_t)c0 * 64 + idx];
    }
    __syncthreads();
    int wv = tid >> 6, lane = tid & 63;
    for (int jj = 0; jj < 16; ++jj) {
        int j = wv * 16 + jj;
        float s = 0.f;
        #pragma unroll
        for (int kk = 0; kk < 4; ++kk) {
            float4 wv4 = *(const float4*)(w1 + (size_t)j * 1024 + kk * 256 + (lane << 2));
            float4 mv  = *(const float4*)&ms[kk * 256 + (lane << 2)];
            s += wv4.x * mv.x + wv4.y * mv.y + wv4.z * mv.z + wv4.w * mv.w;
        }
        #pragma unroll
        for (int o = 32; o; o >>= 1) s += __shfl_down(s, o);
        if (lane == 0) y1[j] = fmaxf(s + b1[j], 0.f);
    }
    __syncthreads();
    if (tid < 64) {
        int c = c0 + tid;
        float s = 0.f;
        #pragma unroll 16
        for (int jj = 0; jj < 64; ++jj) s += y1[jj] * w2t[tid * 65 + jj];
        y2[c] = sigmoidf_(s + b2[c]);
    }
}

// ---------------- K3: fused prep ----------------
// Xsb[c][hw] = bf16(x*y2[c]);  xrb[p][c] = bf16(sigmoid(x*y2[c])) (transposed).
__global__ __launch_bounds__(256) void k_prep(const float* __restrict__ x,
                                              const float* __restrict__ y2,
                                              unsigned short* __restrict__ Xsb,
                                              unsigned short* __restrict__ xrb) {
    __shared__ float T[64][65];
    int tid = threadIdx.x;
    int p0 = blockIdx.x << 6, c0 = blockIdx.y << 6;
    #pragma unroll
    for (int i = 0; i < 4; ++i) {
        int idx = tid + (i << 8);
        int row = idx >> 4;              // channel offset 0..63
        int col = (idx & 15) << 2;       // p offset 0..60
        float sc = y2[c0 + row];
        float4 v = *(const float4*)(x + (size_t)(c0 + row) * 1024 + p0 + col);
        uint2 pk;
        pk.x = (unsigned)f2bf(v.x * sc) | ((unsigned)f2bf(v.y * sc) << 16);
        pk.y = (unsigned)f2bf(v.z * sc) | ((unsigned)f2bf(v.w * sc) << 16);
        *(uint2*)(Xsb + (size_t)(c0 + row) * 1024 + p0 + col) = pk;
        T[col + 0][row] = sigmoidf_(v.x * sc);
        T[col + 1][row] = sigmoidf_(v.y * sc);
        T[col + 2][row] = sigmoidf_(v.z * sc);
        T[col + 3][row] = sigmoidf_(v.w * sc);
    }
    __syncthreads();
    #pragma unroll
    for (int i = 0; i < 4; ++i) {
        int idx = tid + (i << 8);
        int prow = idx >> 4;
        int cc = (idx & 15) << 2;
        uint2 pk;
        pk.x = (unsigned)f2bf(T[prow][cc + 0]) | ((unsigned)f2bf(T[prow][cc + 1]) << 16);
        pk.y = (unsigned)f2bf(T[prow][cc + 2]) | ((unsigned)f2bf(T[prow][cc + 3]) << 16);
        *(uint2*)(xrb + (size_t)(p0 + prow) * 1024 + c0 + cc) = pk;
    }
}

// ---------------- K4: 3x3 local softmax attention (bf16) -> Bt[p][0:1024] ----------------
// val[f] with f = 9*cf + rem == 1024*q + c2 (the reference's reshape reinterpretation).
// Center row is val[9*c2+4] (rem=4 is always in-bounds).
__global__ __launch_bounds__(256) void k_attn(const unsigned short* __restrict__ xrb,
                                              unsigned short* __restrict__ Bt) {
    __shared__ unsigned short val[9216];
    __shared__ float part[9][4];
    int p = blockIdx.x;
    int h = p >> 5, w = p & 31;
    int tid = threadIdx.x;
    int wv = tid >> 6, lane = tid & 63;
    #pragma unroll
    for (int rem = 0; rem < 9; ++rem) {
        int dh = rem / 3 - 1, dw = rem % 3 - 1;
        bool ok = ((unsigned)(h + dh) < 32u) && ((unsigned)(w + dw) < 32u);
        const unsigned short* rp = xrb + (size_t)((h + dh) * 32 + (w + dw)) * 1024;
        #pragma unroll
        for (int j = 0; j < 4; ++j) {
            int cf = tid + (j << 8);
            val[cf * 9 + rem] = ok ? rp[cf] : (unsigned short)0;
        }
    }
    __syncthreads();
    float ctr[4], vv[9][4], lg[9];
    #pragma unroll
    for (int j = 0; j < 4; ++j) ctr[j] = bf2f(val[(4 * tid + j) * 9 + 4]);
    #pragma unroll
    for (int q = 0; q < 9; ++q) {
        uint2 pk = *(const uint2*)&val[q * 1024 + 4 * tid];
        vv[q][0] = bf2f((unsigned short)(pk.x & 0xffffu));
        vv[q][1] = bf2f((unsigned short)(pk.x >> 16));
        vv[q][2] = bf2f((unsigned short)(pk.y & 0xffffu));
        vv[q][3] = bf2f((unsigned short)(pk.y >> 16));
        lg[q] = ctr[0] * vv[q][0] + ctr[1] * vv[q][1]
              + ctr[2] * vv[q][2] + ctr[3] * vv[q][3];
    }
    #pragma unroll
    for (int q = 0; q < 9; ++q) {
        float s = lg[q];
        #pragma unroll
        for (int o = 32; o; o >>= 1) s += __shfl_down(s, o);
        if (lane == 0) part[q][wv] = s;
    }
    __syncthreads();
    float a9[9], mx = -3.4e38f;
    #pragma unroll
    for (int q = 0; q < 9; ++q) {
        a9[q] = part[q][0] + part[q][1] + part[q][2] + part[q][3];
        mx = fmaxf(mx, a9[q]);
    }
    float se = 0.f;
    #pragma unroll
    for (int q = 0; q < 9; ++q) { a9[q] = __expf(a9[q] - mx); se += a9[q]; }
    float inv = 1.f / se;
    float o4[4] = {0.f, 0.f, 0.f, 0.f};
    #pragma unroll
    for (int q = 0; q < 9; ++q) {
        float a = a9[q] * inv;
        #pragma unroll
        for (int j = 0; j < 4; ++j) o4[j] += a * vv[q][j];
    }
    uint2 pk;
    pk.x = (unsigned)f2bf(o4[0]) | ((unsigned)f2bf(o4[1]) << 16);
    pk.y = (unsigned)f2bf(o4[2]) | ((unsigned)f2bf(o4[3]) << 16);
    *(uint2*)(Bt + (size_t)p * 2048 + 4 * tid) = pk;
}

// ---------------- K5: spatial GEMM with in-kernel gaussian A ----------------
// Bt[p][1024+c] = sum_hw K2[p][hw] * Xsb[c][hw], K2[p][hw]=G[p>>5][hw>>5]*G[p&31][hw&31].
__global__ __launch_bounds__(256) void k_gemm_sp(const unsigned short* __restrict__ B,
                                                 unsigned short* __restrict__ Bt) {
    __shared__ unsigned short As[64 * 72];
    __shared__ unsigned short Bs[64 * 72];
    __shared__ float Gs[32][32];
    int tid = threadIdx.x;
    // normalized 1-D gaussian table: 8 lanes per row
    {
        int row = tid >> 3, col0 = (tid & 7) << 2;
        float e[4], s = 0.f;
        #pragma unroll
        for (int j = 0; j < 4; ++j) {
            float d = (float)(row - (col0 + j));
            e[j] = __expf(-d * d / 4.5f);
            s += e[j];
        }
        s += __shfl_xor(s, 4, 8);
        s += __shfl_xor(s, 2, 8);
        s += __shfl_xor(s, 1, 8);
        float is = 1.f / s;
        #pragma unroll
        for (int j = 0; j < 4; ++j) Gs[row][col0 + j] = e[j] * is;
    }
    int wv = tid >> 6, lane = tid & 63;
    int wm = wv & 1, wn = wv >> 1;
    int m0 = blockIdx.y << 6, n0 = blockIdx.x << 6;
    int col = lane & 15, quad = lane >> 4;
    int sm = tid >> 2;
    int sg = (tid & 3) * 2;
    int pm = m0 + sm;
    int rr = pm >> 5, qq = pm & 31;
    v4f acc[2][2];
    #pragma unroll
    for (int i = 0; i < 2; ++i)
        #pragma unroll
        for (int j = 0; j < 2; ++j) acc[i][j] = (v4f){0.f, 0.f, 0.f, 0.f};

    const float4* pb = (const float4*)(B + (size_t)(n0 + sm) * 1024 + sg * 8);
    float4 rb0 = pb[0], rb1 = pb[1];
    for (int it = 0; it < 16; ++it) {
        __syncthreads();
        int k0 = it << 6;
        // generate A tile from the gaussian table
        unsigned pk[8];
        #pragma unroll
        for (int jj = 0; jj < 8; ++jj) {
            int hw0 = k0 + sg * 8 + jj * 2;
            float v0 = Gs[rr][hw0 >> 5] * Gs[qq][hw0 & 31];
            float v1 = Gs[rr][(hw0 + 1) >> 5] * Gs[qq][(hw0 + 1) & 31];
            pk[jj] = (unsigned)f2bf(v0) | ((unsigned)f2bf(v1) << 16);
        }
        *(uint2*)&As[sm * 72 + sg * 8]      = *(uint2*)&pk[0];
        *(uint2*)&As[sm * 72 + sg * 8 + 4]  = *(uint2*)&pk[2];
        *(uint2*)&As[sm * 72 + sg * 8 + 8]  = *(uint2*)&pk[4];
        *(uint2*)&As[sm * 72 + sg * 8 + 12] = *(uint2*)&pk[6];
        *(float4*)&Bs[sm * 72 + sg * 8] = rb0;
        *(float4*)&Bs[sm * 72 + sg * 8 + 8] = rb1;
        __syncthreads();
        if (it + 1 < 16) {
            pb = (const float4*)(B + (size_t)(n0 + sm) * 1024 + ((it + 1) << 6) + sg * 8);
            rb0 = pb[0]; rb1 = pb[1];
        }
        #pragma unroll
        for (int ks = 0; ks < 2; ++ks) {
            int kg = ks * 4 + quad;
            int rA = wm * 32 + col;
            int rB = wn * 32 + col;
            v8s a0 = *(const v8s*)&As[rA * 72 + kg * 8];
            v8s a1 = *(const v8s*)&As[(rA + 16) * 72 + kg * 8];
            v8s b0 = *(const v8s*)&Bs[rB * 72 + kg * 8];
            v8s b1 = *(const v8s*)&Bs[(rB + 16) * 72 + kg * 8];
            acc[0][0] = __builtin_amdgcn_mfma_f32_16x16x32_bf16(a0, b0, acc[0][0], 0, 0, 0);
            acc[0][1] = __builtin_amdgcn_mfma_f32_16x16x32_bf16(a0, b1, acc[0][1], 0, 0, 0);
            acc[1][0] = __builtin_amdgcn_mfma_f32_16x16x32_bf16(a1, b0, acc[1][0], 0, 0, 0);
            acc[1][1] = __builtin_amdgcn_mfma_f32_16x16x32_bf16(a1, b1, acc[1][1], 0, 0, 0);
        }
    }
    #pragma unroll
    for (int mi = 0; mi < 2; ++mi)
        #pragma unroll
        for (int ni = 0; ni < 2; ++ni) {
            int mb = m0 + wm * 32 + mi * 16 + quad * 4;
            int nn = n0 + wn * 32 + ni * 16 + col;
            #pragma unroll
            for (int r = 0; r < 4; ++r)
                Bt[(size_t)(mb + r) * 2048 + 1024 + nn] = f2bf(acc[mi][ni][r]);
        }
}

// ---------------- K6: W fp32 -> bf16 ----------------
__global__ __launch_bounds__(256) void k_packW(const float* __restrict__ W,
                                               unsigned short* __restrict__ Wb) {
    int e = (blockIdx.x * 256 + threadIdx.x) << 2;
    float4 v = *(const float4*)(W + e);
    uint2 pk;
    pk.x = (unsigned)f2bf(v.x) | ((unsigned)f2bf(v.y) << 16);
    pk.y = (unsigned)f2bf(v.z) | ((unsigned)f2bf(v.w) << 16);
    *(uint2*)(Wb + e) = pk;
}

// ---------------- K7: main GEMM out = relu(BN(Wb . Bt^T)) ----------------
__global__ __launch_bounds__(256) void k_gemm_main(
    const unsigned short* __restrict__ A, const unsigned short* __restrict__ B,
    float* __restrict__ outF,
    const float* __restrict__ gamma, const float* __restrict__ beta,
    const float* __restrict__ mu, const float* __restrict__ var) {
    __shared__ unsigned short As[64 * 72];
    __shared__ unsigned short Bs[64 * 72];
    const int K = 2048;
    int tid = threadIdx.x;
    int wv = tid >> 6, lane = tid & 63;
    int wm = wv & 1, wn = wv >> 1;
    int m0 = blockIdx.y << 6, n0 = blockIdx.x << 6;
    int col = lane & 15, quad = lane >> 4;
    int sm = tid >> 2;
    int sg = (tid & 3) * 2;
    v4f acc[2][2];
    #pragma unroll
    for (int i = 0; i < 2; ++i)
        #pragma unroll
        for (int j = 0; j < 2; ++j) acc[i][j] = (v4f){0.f, 0.f, 0.f, 0.f};

    const float4* pa = (const float4*)(A + (size_t)(m0 + sm) * K + sg * 8);
    const float4* pb = (const float4*)(B + (size_t)(n0 + sm) * K + sg * 8);
    float4 ra0 = pa[0], ra1 = pa[1], rb0 = pb[0], rb1 = pb[1];
    for (int it = 0; it < 32; ++it) {
        __syncthreads();
        *(float4*)&As[sm * 72 + sg * 8] = ra0;
        *(float4*)&As[sm * 72 + sg * 8 + 8] = ra1;
        *(float4*)&Bs[sm * 72 + sg * 8] = rb0;
        *(float4*)&Bs[sm * 72 + sg * 8 + 8] = rb1;
        __syncthreads();
        if (it + 1 < 32) {
            int k0 = (it + 1) << 6;
            pa = (const float4*)(A + (size_t)(m0 + sm) * K + k0 + sg * 8);
            pb = (const float4*)(B + (size_t)(n0 + sm) * K + k0 + sg * 8);
            ra0 = pa[0]; ra1 = pa[1];
            rb0 = pb[0]; rb1 = pb[1];
        }
        #pragma unroll
        for (int ks = 0; ks < 2; ++ks) {
            int kg = ks * 4 + quad;
            int rA = wm * 32 + col;
            int rB = wn * 32 + col;
            v8s a0 = *(const v8s*)&As[rA * 72 + kg * 8];
            v8s a1 = *(const v8s*)&As[(rA + 16) * 72 + kg * 8];
            v8s b0 = *(const v8s*)&Bs[rB * 72 + kg * 8];
            v8s b1 = *(const v8s*)&Bs[(rB + 16) * 72 + kg * 8];
            acc[0][0] = __builtin_amdgcn_mfma_f32_16x16x32_bf16(a0, b0, acc[0][0], 0, 0, 0);
            acc[0][1] = __builtin_amdgcn_mfma_f32_16x16x32_bf16(a0, b1, acc[0][1], 0, 0, 0);
            acc[1][0] = __builtin_amdgcn_mfma_f32_16x16x32_bf16(a1, b0, acc[1][0], 0, 0, 0);
            acc[1][1] = __builtin_amdgcn_mfma_f32_16x16x32_bf16(a1, b1, acc[1][1], 0, 0, 0);
        }
    }
    #pragma unroll
    for (int mi = 0; mi < 2; ++mi)
        #pragma unroll
        for (int ni = 0; ni < 2; ++ni) {
            int mb = m0 + wm * 32 + mi * 16 + quad * 4;
            int nn = n0 + wn * 32 + ni * 16 + col;
            #pragma unroll
            for (int r = 0; r < 4; ++r) {
                int mm = mb + r;
                float iv = rsqrtf(var[mm] + 1e-5f);
                float sc = iv * gamma[mm];
                float sh = beta[mm] - mu[mm] * sc;
                outF[((size_t)mm << 10) + nn] = fmaxf(fmaf(acc[mi][ni][r], sc, sh), 0.f);
            }
        }
}

extern "C" void kernel_launch(void* const* d_in, const int* in_sizes, int n_in,
                              void* d_out, int out_size, void* d_ws, size_t ws_size,
                              hipStream_t stream) {
    const float* x     = (const float*)d_in[0];
    const float* w1    = (const float*)d_in[1];
    const float* b1    = (const float*)d_in[2];
    const float* w2    = (const float*)d_in[3];
    const float* b2    = (const float*)d_in[4];
    const float* cw    = (const float*)d_in[5];
    const float* gamma = (const float*)d_in[6];
    const float* beta  = (const float*)d_in[7];
    const float* mu    = (const float*)d_in[8];
    const float* var   = (const float*)d_in[9];
    float* wsf = (float*)d_ws;
    unsigned short* Wb  = (unsigned short*)wsf;                          // 4 MB
    unsigned short* Bt  = (unsigned short*)(wsf + (1 << 20));            // 4 MB [1024][2048]
    unsigned short* Xsb = (unsigned short*)(wsf + (2 << 20));            // 2 MB [c][hw]
    unsigned short* xrb = (unsigned short*)(wsf + (2 << 20) + (1 << 19)); // 2 MB [p][c]
    float* mean = wsf + (3 << 20);
    float* y2   = mean + 1024;
    float* out  = (float*)d_out;

    dim3 g16(16, 16);
    k_mean     <<<1024, 256, 0, stream>>>(x, mean);
    k_se       <<<16, 256, 0, stream>>>(mean, w1, b1, w2, b2, y2);
    k_prep     <<<g16, 256, 0, stream>>>(x, y2, Xsb, xrb);
    k_gemm_sp  <<<g16, 256, 0, stream>>>(Xsb, Bt);
    k_attn     <<<1024, 256, 0, stream>>>(xrb, Bt);
    k_packW    <<<2048, 256, 0, stream>>>(cw, Wb);
    k_gemm_main<<<g16, 256, 0, stream>>>(Wb, Bt, out, gamma, beta, mu, var);
}

// Round 4
// 134.678 us; speedup vs baseline: 2.2836x; 1.0164x over previous
//
#include <hip/hip_runtime.h>
#include <hip/hip_bf16.h>

// 1x1024x32x32: SE block + separable-gaussian spatial pool (A generated in-GEMM)
// + 3x3 local softmax attention (bf16) + 1x1 conv/BN/ReLU (bf16 MFMA GEMM).
// H=W=32, C=1024, r=16, V=1.5.
// Round 4: 5 launches (mean+packW fused; spatial-GEMM+attention fused; wide SE).

typedef __attribute__((ext_vector_type(8))) short v8s;
typedef __attribute__((ext_vector_type(4))) float v4f;

__device__ __forceinline__ float sigmoidf_(float v) {
    return 1.f / (1.f + __expf(-v));
}
__device__ __forceinline__ unsigned short f2bf(float f) {
    unsigned u = __float_as_uint(f);
    u += 0x7fffu + ((u >> 16) & 1u);
    return (unsigned short)(u >> 16);
}
__device__ __forceinline__ float bf2f(unsigned short s) {
    return __uint_as_float(((unsigned)s) << 16);
}

// ---------------- K1: per-channel mean + W fp32->bf16 pack (independent work) ----------------
__global__ __launch_bounds__(256) void k_meanW(const float* __restrict__ x,
                                               const float* __restrict__ W,
                                               float* __restrict__ mean,
                                               unsigned short* __restrict__ Wb) {
    int c = blockIdx.x;
    int tid = threadIdx.x;
    // pack 2048 W elements per block (1024 blocks x 2048 = 2M)
    size_t e0 = (size_t)c * 2048 + (size_t)tid * 8;
    float4 v0 = *(const float4*)(W + e0);
    float4 v1 = *(const float4*)(W + e0 + 4);
    uint4 pk;
    pk.x = (unsigned)f2bf(v0.x) | ((unsigned)f2bf(v0.y) << 16);
    pk.y = (unsigned)f2bf(v0.z) | ((unsigned)f2bf(v0.w) << 16);
    pk.z = (unsigned)f2bf(v1.x) | ((unsigned)f2bf(v1.y) << 16);
    pk.w = (unsigned)f2bf(v1.z) | ((unsigned)f2bf(v1.w) << 16);
    *(uint4*)(Wb + e0) = pk;
    // mean of channel c
    const float* xp = x + (size_t)c * 1024;
    float s = xp[tid] + xp[tid + 256] + xp[tid + 512] + xp[tid + 768];
    #pragma unroll
    for (int o = 32; o; o >>= 1) s += __shfl_down(s, o);
    __shared__ float wsum[4];
    if ((tid & 63) == 0) wsum[tid >> 6] = s;
    __syncthreads();
    if (tid == 0) mean[c] = (wsum[0] + wsum[1] + wsum[2] + wsum[3]) * (1.f / 1024.f);
}

// ---------------- K2: SE MLP, 16 blocks x 1024 threads (16 waves) ----------------
// Layer 1: wave wv computes hidden j = wv*4+jj (serial depth 4, coalesced full-wave dots).
// Layer 2: 64 outputs/block, 16 lanes per output.
__global__ __launch_bounds__(1024) void k_se(const float* __restrict__ mean,
                                             const float* __restrict__ w1,
                                             const float* __restrict__ b1,
                                             const float* __restrict__ w2,
                                             const float* __restrict__ b2,
                                             float* __restrict__ y2) {
    __shared__ float ms[1024];
    __shared__ float y1[64];
    __shared__ float w2t[64 * 65];
    int tid = threadIdx.x;
    int c0 = blockIdx.x << 6;
    ms[tid] = mean[tid];
    #pragma unroll
    for (int i = 0; i < 4; ++i) {
        int idx = tid + (i << 10);                      // 4096 floats
        w2t[(idx >> 6) * 65 + (idx & 63)] = w2[(size_t)c0 * 64 + idx];
    }
    __syncthreads();
    int wv = tid >> 6, lane = tid & 63;
    #pragma unroll
    for (int jj = 0; jj < 4; ++jj) {
        int j = (wv << 2) + jj;
        float s = 0.f;
        #pragma unroll
        for (int kk = 0; kk < 4; ++kk) {
            float4 wv4 = *(const float4*)(w1 + (size_t)j * 1024 + kk * 256 + (lane << 2));
            float4 mv  = *(const float4*)&ms[kk * 256 + (lane << 2)];
            s += wv4.x * mv.x + wv4.y * mv.y + wv4.z * mv.z + wv4.w * mv.w;
        }
        #pragma unroll
        for (int o = 32; o; o >>= 1) s += __shfl_down(s, o);
        if (lane == 0) y1[j] = fmaxf(s + b1[j], 0.f);
    }
    __syncthreads();
    int o = tid >> 4, l = tid & 15;                     // 64 outputs x 16 lanes
    float s = 0.f;
    #pragma unroll
    for (int jj = 0; jj < 4; ++jj) s += y1[l + (jj << 4)] * w2t[o * 65 + l + (jj << 4)];
    #pragma unroll
    for (int o2 = 8; o2; o2 >>= 1) s += __shfl_down(s, o2, 16);
    if (l == 0) y2[c0 + o] = sigmoidf_(s + b2[c0 + o]);
}

// ---------------- K3: fused prep ----------------
// Xsb[c][hw] = bf16(x*y2[c]);  xrb[p][c] = bf16(sigmoid(x*y2[c])) (transposed).
__global__ __launch_bounds__(256) void k_prep(const float* __restrict__ x,
                                              const float* __restrict__ y2,
                                              unsigned short* __restrict__ Xsb,
                                              unsigned short* __restrict__ xrb) {
    __shared__ float T[64][65];
    int tid = threadIdx.x;
    int p0 = blockIdx.x << 6, c0 = blockIdx.y << 6;
    #pragma unroll
    for (int i = 0; i < 4; ++i) {
        int idx = tid + (i << 8);
        int row = idx >> 4;
        int col = (idx & 15) << 2;
        float sc = y2[c0 + row];
        float4 v = *(const float4*)(x + (size_t)(c0 + row) * 1024 + p0 + col);
        uint2 pk;
        pk.x = (unsigned)f2bf(v.x * sc) | ((unsigned)f2bf(v.y * sc) << 16);
        pk.y = (unsigned)f2bf(v.z * sc) | ((unsigned)f2bf(v.w * sc) << 16);
        *(uint2*)(Xsb + (size_t)(c0 + row) * 1024 + p0 + col) = pk;
        T[col + 0][row] = sigmoidf_(v.x * sc);
        T[col + 1][row] = sigmoidf_(v.y * sc);
        T[col + 2][row] = sigmoidf_(v.z * sc);
        T[col + 3][row] = sigmoidf_(v.w * sc);
    }
    __syncthreads();
    #pragma unroll
    for (int i = 0; i < 4; ++i) {
        int idx = tid + (i << 8);
        int prow = idx >> 4;
        int cc = (idx & 15) << 2;
        uint2 pk;
        pk.x = (unsigned)f2bf(T[prow][cc + 0]) | ((unsigned)f2bf(T[prow][cc + 1]) << 16);
        pk.y = (unsigned)f2bf(T[prow][cc + 2]) | ((unsigned)f2bf(T[prow][cc + 3]) << 16);
        *(uint2*)(xrb + (size_t)(p0 + prow) * 1024 + c0 + cc) = pk;
    }
}

// ---------------- K4: fused spatial GEMM (blocks 0..255) + attention (blocks 256..1279) ----------------
union SMem {
    struct { unsigned short As[64 * 72]; unsigned short Bs[64 * 72]; float Gs[32][32]; } sp;
    struct { unsigned short val[9216]; float part[9][4]; } at;
};

__global__ __launch_bounds__(256) void k_spattn(const unsigned short* __restrict__ Xsb,
                                                const unsigned short* __restrict__ xrb,
                                                unsigned short* __restrict__ Bt) {
    __shared__ SMem sm;
    int tid = threadIdx.x;
    int bx = blockIdx.x;
    if (bx < 256) {
        // ---- spatial GEMM: Bt[p][1024+c] = sum_hw K2[p][hw]*Xsb[c][hw],
        //      K2[p][hw] = G[p>>5][hw>>5]*G[p&31][hw&31], G generated in-kernel.
        {
            int row = tid >> 3, col0 = (tid & 7) << 2;
            float e[4], s = 0.f;
            #pragma unroll
            for (int j = 0; j < 4; ++j) {
                float d = (float)(row - (col0 + j));
                e[j] = __expf(-d * d / 4.5f);
                s += e[j];
            }
            s += __shfl_xor(s, 4, 8);
            s += __shfl_xor(s, 2, 8);
            s += __shfl_xor(s, 1, 8);
            float is = 1.f / s;
            #pragma unroll
            for (int j = 0; j < 4; ++j) sm.sp.Gs[row][col0 + j] = e[j] * is;
        }
        int wv = tid >> 6, lane = tid & 63;
        int wm = wv & 1, wn = wv >> 1;
        int m0 = (bx >> 4) << 6, n0 = (bx & 15) << 6;
        int col = lane & 15, quad = lane >> 4;
        int smi = tid >> 2;
        int sg = (tid & 3) * 2;
        int pm = m0 + smi;
        int rr = pm >> 5, qq = pm & 31;
        v4f acc[2][2];
        #pragma unroll
        for (int i = 0; i < 2; ++i)
            #pragma unroll
            for (int j = 0; j < 2; ++j) acc[i][j] = (v4f){0.f, 0.f, 0.f, 0.f};
        const float4* pb = (const float4*)(Xsb + (size_t)(n0 + smi) * 1024 + sg * 8);
        float4 rb0 = pb[0], rb1 = pb[1];
        for (int it = 0; it < 16; ++it) {
            __syncthreads();
            int k0 = it << 6;
            unsigned pk[8];
            #pragma unroll
            for (int jj = 0; jj < 8; ++jj) {
                int hw0 = k0 + sg * 8 + jj * 2;
                float v0 = sm.sp.Gs[rr][hw0 >> 5] * sm.sp.Gs[qq][hw0 & 31];
                float v1 = sm.sp.Gs[rr][(hw0 + 1) >> 5] * sm.sp.Gs[qq][(hw0 + 1) & 31];
                pk[jj] = (unsigned)f2bf(v0) | ((unsigned)f2bf(v1) << 16);
            }
            *(uint2*)&sm.sp.As[smi * 72 + sg * 8]      = *(uint2*)&pk[0];
            *(uint2*)&sm.sp.As[smi * 72 + sg * 8 + 4]  = *(uint2*)&pk[2];
            *(uint2*)&sm.sp.As[smi * 72 + sg * 8 + 8]  = *(uint2*)&pk[4];
            *(uint2*)&sm.sp.As[smi * 72 + sg * 8 + 12] = *(uint2*)&pk[6];
            *(float4*)&sm.sp.Bs[smi * 72 + sg * 8] = rb0;
            *(float4*)&sm.sp.Bs[smi * 72 + sg * 8 + 8] = rb1;
            __syncthreads();
            if (it + 1 < 16) {
                pb = (const float4*)(Xsb + (size_t)(n0 + smi) * 1024 + ((it + 1) << 6) + sg * 8);
                rb0 = pb[0]; rb1 = pb[1];
            }
            #pragma unroll
            for (int ks = 0; ks < 2; ++ks) {
                int kg = ks * 4 + quad;
                int rA = wm * 32 + col;
                int rB = wn * 32 + col;
                v8s a0 = *(const v8s*)&sm.sp.As[rA * 72 + kg * 8];
                v8s a1 = *(const v8s*)&sm.sp.As[(rA + 16) * 72 + kg * 8];
                v8s b0 = *(const v8s*)&sm.sp.Bs[rB * 72 + kg * 8];
                v8s b1 = *(const v8s*)&sm.sp.Bs[(rB + 16) * 72 + kg * 8];
                acc[0][0] = __builtin_amdgcn_mfma_f32_16x16x32_bf16(a0, b0, acc[0][0], 0, 0, 0);
                acc[0][1] = __builtin_amdgcn_mfma_f32_16x16x32_bf16(a0, b1, acc[0][1], 0, 0, 0);
                acc[1][0] = __builtin_amdgcn_mfma_f32_16x16x32_bf16(a1, b0, acc[1][0], 0, 0, 0);
                acc[1][1] = __builtin_amdgcn_mfma_f32_16x16x32_bf16(a1, b1, acc[1][1], 0, 0, 0);
            }
        }
        #pragma unroll
        for (int mi = 0; mi < 2; ++mi)
            #pragma unroll
            for (int ni = 0; ni < 2; ++ni) {
                int mb = m0 + wm * 32 + mi * 16 + quad * 4;
                int nn = n0 + wn * 32 + ni * 16 + col;
                #pragma unroll
                for (int r = 0; r < 4; ++r)
                    Bt[(size_t)(mb + r) * 2048 + 1024 + nn] = f2bf(acc[mi][ni][r]);
            }
    } else {
        // ---- 3x3 local softmax attention for position p = bx-256 ----
        // val[f] with f = 9*cf+rem == 1024*q + c2 (reference reshape reinterpretation).
        int p = bx - 256;
        int h = p >> 5, w = p & 31;
        int wv = tid >> 6, lane = tid & 63;
        #pragma unroll
        for (int rem = 0; rem < 9; ++rem) {
            int dh = rem / 3 - 1, dw = rem % 3 - 1;
            bool ok = ((unsigned)(h + dh) < 32u) && ((unsigned)(w + dw) < 32u);
            const unsigned short* rp = xrb + (size_t)((h + dh) * 32 + (w + dw)) * 1024;
            #pragma unroll
            for (int j = 0; j < 4; ++j) {
                int cf = tid + (j << 8);
                sm.at.val[cf * 9 + rem] = ok ? rp[cf] : (unsigned short)0;
            }
        }
        __syncthreads();
        float ctr[4], vv[9][4], lg[9];
        #pragma unroll
        for (int j = 0; j < 4; ++j) ctr[j] = bf2f(sm.at.val[(4 * tid + j) * 9 + 4]);
        #pragma unroll
        for (int q = 0; q < 9; ++q) {
            uint2 pk = *(const uint2*)&sm.at.val[q * 1024 + 4 * tid];
            vv[q][0] = bf2f((unsigned short)(pk.x & 0xffffu));
            vv[q][1] = bf2f((unsigned short)(pk.x >> 16));
            vv[q][2] = bf2f((unsigned short)(pk.y & 0xffffu));
            vv[q][3] = bf2f((unsigned short)(pk.y >> 16));
            lg[q] = ctr[0] * vv[q][0] + ctr[1] * vv[q][1]
                  + ctr[2] * vv[q][2] + ctr[3] * vv[q][3];
        }
        #pragma unroll
        for (int q = 0; q < 9; ++q) {
            float s = lg[q];
            #pragma unroll
            for (int o = 32; o; o >>= 1) s += __shfl_down(s, o);
            if (lane == 0) sm.at.part[q][wv] = s;
        }
        __syncthreads();
        float a9[9], mx = -3.4e38f;
        #pragma unroll
        for (int q = 0; q < 9; ++q) {
            a9[q] = sm.at.part[q][0] + sm.at.part[q][1] + sm.at.part[q][2] + sm.at.part[q][3];
            mx = fmaxf(mx, a9[q]);
        }
        float se = 0.f;
        #pragma unroll
        for (int q = 0; q < 9; ++q) { a9[q] = __expf(a9[q] - mx); se += a9[q]; }
        float inv = 1.f / se;
        float o4[4] = {0.f, 0.f, 0.f, 0.f};
        #pragma unroll
        for (int q = 0; q < 9; ++q) {
            float a = a9[q] * inv;
            #pragma unroll
            for (int j = 0; j < 4; ++j) o4[j] += a * vv[q][j];
        }
        uint2 pk;
        pk.x = (unsigned)f2bf(o4[0]) | ((unsigned)f2bf(o4[1]) << 16);
        pk.y = (unsigned)f2bf(o4[2]) | ((unsigned)f2bf(o4[3]) << 16);
        *(uint2*)(Bt + (size_t)p * 2048 + 4 * tid) = pk;
    }
}

// ---------------- K5: main GEMM out = relu(BN(Wb . Bt^T)) ----------------
__global__ __launch_bounds__(256) void k_gemm_main(
    const unsigned short* __restrict__ A, const unsigned short* __restrict__ B,
    float* __restrict__ outF,
    const float* __restrict__ gamma, const float* __restrict__ beta,
    const float* __restrict__ mu, const float* __restrict__ var) {
    __shared__ unsigned short As[64 * 72];
    __shared__ unsigned short Bs[64 * 72];
    const int K = 2048;
    int tid = threadIdx.x;
    int wv = tid >> 6, lane = tid & 63;
    int wm = wv & 1, wn = wv >> 1;
    int m0 = blockIdx.y << 6, n0 = blockIdx.x << 6;
    int col = lane & 15, quad = lane >> 4;
    int sm = tid >> 2;
    int sg = (tid & 3) * 2;
    v4f acc[2][2];
    #pragma unroll
    for (int i = 0; i < 2; ++i)
        #pragma unroll
        for (int j = 0; j < 2; ++j) acc[i][j] = (v4f){0.f, 0.f, 0.f, 0.f};

    const float4* pa = (const float4*)(A + (size_t)(m0 + sm) * K + sg * 8);
    const float4* pb = (const float4*)(B + (size_t)(n0 + sm) * K + sg * 8);
    float4 ra0 = pa[0], ra1 = pa[1], rb0 = pb[0], rb1 = pb[1];
    for (int it = 0; it < 32; ++it) {
        __syncthreads();
        *(float4*)&As[sm * 72 + sg * 8] = ra0;
        *(float4*)&As[sm * 72 + sg * 8 + 8] = ra1;
        *(float4*)&Bs[sm * 72 + sg * 8] = rb0;
        *(float4*)&Bs[sm * 72 + sg * 8 + 8] = rb1;
        __syncthreads();
        if (it + 1 < 32) {
            int k0 = (it + 1) << 6;
            pa = (const float4*)(A + (size_t)(m0 + sm) * K + k0 + sg * 8);
            pb = (const float4*)(B + (size_t)(n0 + sm) * K + k0 + sg * 8);
            ra0 = pa[0]; ra1 = pa[1];
            rb0 = pb[0]; rb1 = pb[1];
        }
        #pragma unroll
        for (int ks = 0; ks < 2; ++ks) {
            int kg = ks * 4 + quad;
            int rA = wm * 32 + col;
            int rB = wn * 32 + col;
            v8s a0 = *(const v8s*)&As[rA * 72 + kg * 8];
            v8s a1 = *(const v8s*)&As[(rA + 16) * 72 + kg * 8];
            v8s b0 = *(const v8s*)&Bs[rB * 72 + kg * 8];
            v8s b1 = *(const v8s*)&Bs[(rB + 16) * 72 + kg * 8];
            acc[0][0] = __builtin_amdgcn_mfma_f32_16x16x32_bf16(a0, b0, acc[0][0], 0, 0, 0);
            acc[0][1] = __builtin_amdgcn_mfma_f32_16x16x32_bf16(a0, b1, acc[0][1], 0, 0, 0);
            acc[1][0] = __builtin_amdgcn_mfma_f32_16x16x32_bf16(a1, b0, acc[1][0], 0, 0, 0);
            acc[1][1] = __builtin_amdgcn_mfma_f32_16x16x32_bf16(a1, b1, acc[1][1], 0, 0, 0);
        }
    }
    #pragma unroll
    for (int mi = 0; mi < 2; ++mi)
        #pragma unroll
        for (int ni = 0; ni < 2; ++ni) {
            int mb = m0 + wm * 32 + mi * 16 + quad * 4;
            int nn = n0 + wn * 32 + ni * 16 + col;
            #pragma unroll
            for (int r = 0; r < 4; ++r) {
                int mm = mb + r;
                float iv = rsqrtf(var[mm] + 1e-5f);
                float sc = iv * gamma[mm];
                float sh = beta[mm] - mu[mm] * sc;
                outF[((size_t)mm << 10) + nn] = fmaxf(fmaf(acc[mi][ni][r], sc, sh), 0.f);
            }
        }
}

extern "C" void kernel_launch(void* const* d_in, const int* in_sizes, int n_in,
                              void* d_out, int out_size, void* d_ws, size_t ws_size,
                              hipStream_t stream) {
    const float* x     = (const float*)d_in[0];
    const float* w1    = (const float*)d_in[1];
    const float* b1    = (const float*)d_in[2];
    const float* w2    = (const float*)d_in[3];
    const float* b2    = (const float*)d_in[4];
    const float* cw    = (const float*)d_in[5];
    const float* gamma = (const float*)d_in[6];
    const float* beta  = (const float*)d_in[7];
    const float* mu    = (const float*)d_in[8];
    const float* var   = (const float*)d_in[9];
    float* wsf = (float*)d_ws;
    unsigned short* Wb  = (unsigned short*)wsf;                           // 4 MB
    unsigned short* Bt  = (unsigned short*)(wsf + (1 << 20));             // 4 MB [1024][2048]
    unsigned short* Xsb = (unsigned short*)(wsf + (2 << 20));             // 2 MB [c][hw]
    unsigned short* xrb = (unsigned short*)(wsf + (2 << 20) + (1 << 19)); // 2 MB [p][c]
    float* mean = wsf + (3 << 20);
    float* y2   = mean + 1024;
    float* out  = (float*)d_out;

    dim3 g16(16, 16);
    k_meanW    <<<1024, 256, 0, stream>>>(x, cw, mean, Wb);
    k_se       <<<16, 1024, 0, stream>>>(mean, w1, b1, w2, b2, y2);
    k_prep     <<<g16, 256, 0, stream>>>(x, y2, Xsb, xrb);
    k_spattn   <<<1280, 256, 0, stream>>>(Xsb, xrb, Bt);
    k_gemm_main<<<g16, 256, 0, stream>>>(Wb, Bt, out, gamma, beta, mu, var);
}